// Round 5
// baseline (109.244 us; speedup 1.0000x reference)
//
#include <hip/hip_runtime.h>

// KVCache scatter: B=8, L=4096, H=16, D=64, Q=1024 (fp32)
// out = [k_out (B,L,H,D) | v_out (B,L,H,D)] flat fp32
//
// R5: K/V SPLIT ACROSS BLOCKS. Even blocks copy K rows, odd blocks copy V
// rows -> each block is a pure 2-stream copier (1 load + 1 store per thread
// per row), matching the shape of the 6.29 TB/s float4-copy ceiling probe.
//   Per block: scan its batch's 1024 positions (4 KB, L2-resident) into a
//   32-entry LDS inverse map, then 32 row-copies (row source = val row if
//   scattered else cache row; branch is wave-uniform).
// Traffic floor: 268 MB write + 268 MB read = 536 MB -> 85 us @ 6.29 TB/s.

#define KB 8
#define KL 4096
#define KH 16
#define KD 64
#define KQ 1024

typedef float f32x4 __attribute__((ext_vector_type(4)));

static constexpr int ROW4 = (KH * KD) / 4;        // 256 f32x4 per row
static constexpr int RPB  = 32;                    // rows per block
static constexpr int NCH  = (KB * KL) / RPB;       // 1024 chunks per tensor
static constexpr long long TOT = (long long)KB * KL * KH * KD;  // floats per tensor

__global__ __launch_bounds__(256) void kv_scatter_split(
    const f32x4* __restrict__ kc, const f32x4* __restrict__ vc,
    const f32x4* __restrict__ kv, const f32x4* __restrict__ vv,
    const int* __restrict__ pos,
    f32x4* __restrict__ ko, f32x4* __restrict__ vo)
{
    __shared__ int inv_s[RPB];
    const int t      = threadIdx.x;
    const int tensor = blockIdx.x & 1;             // 0 = K, 1 = V
    const int chunk  = blockIdx.x >> 1;
    const int row_lo = chunk * RPB;                // global row (b*L + l_lo)
    const int b      = row_lo >> 12;               // / KL
    const int l_lo   = row_lo & (KL - 1);

    const f32x4* __restrict__ cache = tensor ? vc : kc;
    const f32x4* __restrict__ val   = tensor ? vv : kv;
    f32x4* __restrict__ out         = tensor ? vo : ko;

    if (t < RPB) inv_s[t] = -1;
    __syncthreads();
    const int* prow = pos + b * KQ;
    #pragma unroll
    for (int j = t; j < KQ; j += 256) {
        int p = prow[j] - 1;                       // 1-indexed -> 0-indexed slot
        unsigned d = (unsigned)(p - l_lo);
        if (d < (unsigned)RPB) inv_s[d] = j;
    }
    __syncthreads();

    const long long vbase = (long long)(b * KQ) << 8;   // val row base (f32x4)
    #pragma unroll
    for (int k = 0; k < RPB; ++k) {
        int q = inv_s[k];                          // wave-uniform
        long long o = ((long long)(row_lo + k) << 8) + t;
        f32x4 x;
        if (q >= 0)
            x = __builtin_nontemporal_load(&val[vbase + ((long long)q << 8) + t]);
        else
            x = __builtin_nontemporal_load(&cache[o]);
        __builtin_nontemporal_store(x, &out[o]);
    }
}

extern "C" void kernel_launch(void* const* d_in, const int* in_sizes, int n_in,
                              void* d_out, int out_size, void* d_ws, size_t ws_size,
                              hipStream_t stream) {
    const float* kc  = (const float*)d_in[0];
    const float* vc  = (const float*)d_in[1];
    const float* kv  = (const float*)d_in[2];
    const float* vv  = (const float*)d_in[3];
    const int*   pos = (const int*)d_in[4];

    float* ko = (float*)d_out;
    float* vo = ko + TOT;

    kv_scatter_split<<<2 * NCH, 256, 0, stream>>>(
        (const f32x4*)kc, (const f32x4*)vc,
        (const f32x4*)kv, (const f32x4*)vv,
        pos, (f32x4*)ko, (f32x4*)vo);
}